// Round 1
// baseline (634.938 us; speedup 1.0000x reference)
//
#include <hip/hip_runtime.h>
#include <hip/hip_bf16.h>

typedef __bf16 bf16;
typedef unsigned short u16;
typedef bf16 bf16x8 __attribute__((ext_vector_type(8)));
typedef bf16 bf16x4 __attribute__((ext_vector_type(4)));
typedef u16  u16x8  __attribute__((ext_vector_type(8)));
typedef float f32x4 __attribute__((ext_vector_type(4)));

#define MFMA16(a,b,c) __builtin_amdgcn_mfma_f32_16x16x32_bf16((a),(b),(c),0,0,0)

// ---------------------------------------------------------------- converts
__global__ void cvt_x(const float* __restrict__ x, bf16* __restrict__ xb) {
    int idx = blockIdx.x * 256 + threadIdx.x;      // 2M threads, 4 elts each
    float4 v = ((const float4*)x)[idx];
    bf16x4 o;
    o[0] = (bf16)v.x; o[1] = (bf16)v.y; o[2] = (bf16)v.z; o[3] = (bf16)v.w;
    ((bf16x4*)xb)[idx] = o;
}

// W (f32 [c][d]) -> bf16 transposed [which][d][c]
__global__ void cvt_w(const float* __restrict__ Wq, const float* __restrict__ Wk,
                      const float* __restrict__ Wv, bf16* __restrict__ Wbt) {
    int idx = blockIdx.x * 256 + threadIdx.x;      // 3*65536 threads
    int which = idx >> 16;
    int rem = idx & 65535;
    int c = rem >> 8, d = rem & 255;
    const float* W = (which == 0) ? Wq : (which == 1) ? Wk : Wv;
    Wbt[(size_t)which * 65536 + d * 256 + c] = (bf16)W[c * 256 + d];
}

// ---------------------------------------------------------------- QKV GEMM
// [32768 x 256] @ [256 x 256] -> Q/K/V bf16.  64x64 tile, 4 waves, K in 2 halves.
__global__ __launch_bounds__(256, 2)
void qkv_gemm(const bf16* __restrict__ xb, const bf16* __restrict__ Wbt,
              bf16* __restrict__ Qb, bf16* __restrict__ Kb, bf16* __restrict__ Vb) {
    __shared__ __align__(16) u16 lA[64 * 136];
    __shared__ __align__(16) u16 lB[64 * 136];
    int mt = blockIdx.x, nt = blockIdx.y, which = blockIdx.z;
    int tid = threadIdx.x, wv = tid >> 6, lane = tid & 63;
    int l15 = lane & 15, quad = lane >> 4;

    f32x4 acc[4] = {};
    const bf16* Ab = xb + (size_t)(mt * 64) * 256;
    const bf16* Bb = Wbt + (size_t)which * 65536 + (size_t)(nt * 64) * 256;

    for (int kh = 0; kh < 2; kh++) {
        __syncthreads();
        int row = tid >> 2, c0 = (tid & 3) * 32;
        #pragma unroll
        for (int i = 0; i < 4; i++) {
            *(bf16x8*)((bf16*)lA + row * 136 + c0 + i * 8) =
                *(const bf16x8*)(Ab + row * 256 + kh * 128 + c0 + i * 8);
            *(bf16x8*)((bf16*)lB + row * 136 + c0 + i * 8) =
                *(const bf16x8*)(Bb + row * 256 + kh * 128 + c0 + i * 8);
        }
        __syncthreads();
        #pragma unroll
        for (int ks = 0; ks < 4; ks++) {
            bf16x8 a = *(const bf16x8*)((bf16*)lA + (wv * 16 + l15) * 136 + ks * 32 + quad * 8);
            #pragma unroll
            for (int ns = 0; ns < 4; ns++) {
                bf16x8 b = *(const bf16x8*)((bf16*)lB + (ns * 16 + l15) * 136 + ks * 32 + quad * 8);
                acc[ns] = MFMA16(a, b, acc[ns]);
            }
        }
    }
    bf16* outp = (which == 0) ? Qb : (which == 1) ? Kb : Vb;
    #pragma unroll
    for (int ns = 0; ns < 4; ns++)
        #pragma unroll
        for (int r = 0; r < 4; r++) {
            int tok = mt * 64 + wv * 16 + quad * 4 + r;
            int col = nt * 64 + ns * 16 + l15;
            outp[(size_t)tok * 256 + col] = (bf16)acc[ns][r];
        }
}

// ---------------------------------------------------------------- attention
// block = 64 q-rows of one segment; 4 waves x 16 rows; K-tile = 64 keys.
__global__ __launch_bounds__(256, 2)
void attn(const bf16* __restrict__ Qb, const bf16* __restrict__ Kb,
          const bf16* __restrict__ Vb, float* __restrict__ out,
          float* __restrict__ sums) {
    // union region: K-tile [64][264] (16896 u16) OR V^T-tile [256][72] (18432 u16)
    __shared__ __align__(16) u16 ldsKV[256 * 72];
    __shared__ __align__(16) u16 ldsP[4 * 16 * 72];

    int qt = 31 - (int)blockIdx.x;          // heavy tiles first
    int seg = blockIdx.y;
    int wwin, rr, s, b;
    if (seg < 16)      { wwin = 2048; rr = 1; s = seg >> 2;        b = seg & 3; }
    else if (seg < 24) { wwin = 4096; rr = 2; s = (seg - 16) >> 2; b = (seg - 16) & 3; }
    else               { wwin = 8192; rr = 4; s = 0;               b = seg - 24; }
    const size_t base = (size_t)b * 8192 + (size_t)s * wwin;  // token = base + j*rr

    int tid = threadIdx.x, wv = tid >> 6, lane = tid & 63;
    int l15 = lane & 15, quad = lane >> 4;

    // Q fragments (A-layout: m = l15, k = quad*8 + j), 16 rows per wave, K=256
    int qi_lane = qt * 64 + wv * 16 + l15;
    const bf16* qptr = Qb + (base + (size_t)qi_lane * rr) * 256 + quad * 8;
    bf16x8 qf[8];
    #pragma unroll
    for (int ks = 0; ks < 8; ks++) qf[ks] = *(const bf16x8*)(qptr + ks * 32);

    f32x4 o[16] = {};
    float m_run[4] = {-1e30f, -1e30f, -1e30f, -1e30f};
    float l_run[4] = {0.f, 0.f, 0.f, 0.f};

    bf16* K_l = (bf16*)ldsKV;            // [64][264]
    bf16* V_l = (bf16*)ldsKV;            // [256][72] (time-shared with K)
    bf16* P_l = (bf16*)ldsP + wv * 16 * 72;

    const int nkt = qt + 1;
    for (int kt = 0; kt < nkt; kt++) {
        const int j0 = kt * 64;
        __syncthreads();                 // prev iter done reading V
        {   // stage K [64][264]
            int row = tid >> 2, c0 = (tid & 3) * 64;
            const bf16* kp = Kb + (base + (size_t)(j0 + row) * rr) * 256 + c0;
            bf16* kd = K_l + row * 264 + c0;
            #pragma unroll
            for (int i = 0; i < 8; i++)
                *(bf16x8*)(kd + i * 8) = *(const bf16x8*)(kp + i * 8);
        }
        __syncthreads();
        // S = Q K^T  (16 x 64 per wave)
        f32x4 sf[4] = {};
        #pragma unroll
        for (int ks = 0; ks < 8; ks++) {
            #pragma unroll
            for (int ns = 0; ns < 4; ns++) {
                bf16x8 kf = *(const bf16x8*)(K_l + (ns * 16 + l15) * 264 + ks * 32 + quad * 8);
                sf[ns] = MFMA16(qf[ks], kf, sf[ns]);
            }
        }
        // scale + causal mask (mask only possible on the diagonal tile)
        #pragma unroll
        for (int ns = 0; ns < 4; ns++)
            #pragma unroll
            for (int r = 0; r < 4; r++) {
                float v = sf[ns][r] * 0.0625f;       // 1/sqrt(256)
                if (kt == qt) {
                    int jl = ns * 16 + l15;
                    int qi = wv * 16 + quad * 4 + r;
                    if (jl > qi) v = -1e30f;
                }
                sf[ns][r] = v;
            }
        // online softmax (row = quad*4+r spread over 16 lanes of same quad)
        float alpha[4];
        #pragma unroll
        for (int r = 0; r < 4; r++) {
            float mx = fmaxf(fmaxf(sf[0][r], sf[1][r]), fmaxf(sf[2][r], sf[3][r]));
            #pragma unroll
            for (int off = 1; off < 16; off <<= 1) mx = fmaxf(mx, __shfl_xor(mx, off));
            float mnew = fmaxf(m_run[r], mx);
            float a = __expf(m_run[r] - mnew);
            m_run[r] = mnew;
            float rs = 0.f;
            #pragma unroll
            for (int ns = 0; ns < 4; ns++) {
                float p = __expf(sf[ns][r] - mnew);
                sf[ns][r] = p;
                rs += p;
            }
            #pragma unroll
            for (int off = 1; off < 16; off <<= 1) rs += __shfl_xor(rs, off);
            l_run[r] = l_run[r] * a + rs;
            alpha[r] = a;
        }
        #pragma unroll
        for (int nf = 0; nf < 16; nf++)
            #pragma unroll
            for (int r = 0; r < 4; r++) o[nf][r] *= alpha[r];
        // P (C-layout) -> LDS, re-read below in A-layout
        #pragma unroll
        for (int ns = 0; ns < 4; ns++)
            #pragma unroll
            for (int r = 0; r < 4; r++)
                P_l[(quad * 4 + r) * 72 + ns * 16 + l15] = (bf16)sf[ns][r];
        __syncthreads();                 // all waves done reading K
        {   // stage V^T [256][72]: pack two adjacent keys into one b32 write
            int jj0 = (tid & 31) * 2, d0 = (tid >> 5) << 3;
            const u16* vp0 = (const u16*)Vb + (base + (size_t)(j0 + jj0) * rr) * 256;
            const u16* vp1 = (const u16*)Vb + (base + (size_t)(j0 + jj0 + 1) * rr) * 256;
            #pragma unroll
            for (int db = 0; db < 4; db++) {
                int d = d0 + db * 64;
                u16x8 a0 = *(const u16x8*)(vp0 + d);
                u16x8 a1 = *(const u16x8*)(vp1 + d);
                #pragma unroll
                for (int e = 0; e < 8; e++) {
                    unsigned pk = (unsigned)a0[e] | ((unsigned)a1[e] << 16);
                    *(unsigned*)((u16*)V_l + (size_t)(d + e) * 72 + jj0) = pk;
                }
            }
        }
        __syncthreads();
        // O += P V   (P: A-layout from LDS; V^T: B-layout contiguous along keys)
        #pragma unroll
        for (int kk = 0; kk < 2; kk++) {
            bf16x8 pa = *(const bf16x8*)(P_l + l15 * 72 + kk * 32 + quad * 8);
            #pragma unroll
            for (int nf = 0; nf < 16; nf++) {
                bf16x8 vf = *(const bf16x8*)(V_l + (nf * 16 + l15) * 72 + kk * 32 + quad * 8);
                o[nf] = MFMA16(pa, vf, o[nf]);
            }
        }
    }
    // epilogue: contribution = acc * exp(m);  denom = l * exp(m)
    #pragma unroll
    for (int r = 0; r < 4; r++) {
        float wsc = __expf(m_run[r]);
        float denom = l_run[r] * wsc;
        int qi = qt * 64 + wv * 16 + quad * 4 + r;
        size_t tok = base + (size_t)qi * rr;
        if (l15 == 0) atomicAdd(sums + tok, denom);
        float* orow = out + tok * 256;
        #pragma unroll
        for (int nf = 0; nf < 16; nf++)
            atomicAdd(orow + nf * 16 + l15, o[nf][r] * wsc);
    }
}

// ---------------------------------------------------------------- finalize
__global__ void finalize(float* __restrict__ out, const float* __restrict__ sums) {
    int idx = blockIdx.x * 256 + threadIdx.x;   // 2M float4
    float inv = 1.0f / sums[idx >> 6];
    float4 v = ((float4*)out)[idx];
    v.x *= inv; v.y *= inv; v.z *= inv; v.w *= inv;
    ((float4*)out)[idx] = v;
}

// ---------------------------------------------------------------- launch
extern "C" void kernel_launch(void* const* d_in, const int* in_sizes, int n_in,
                              void* d_out, int out_size, void* d_ws, size_t ws_size,
                              hipStream_t stream) {
    const float* x  = (const float*)d_in[0];
    const float* Wq = (const float*)d_in[1];
    const float* Wk = (const float*)d_in[2];
    const float* Wv = (const float*)d_in[3];
    float* out = (float*)d_out;

    char* ws = (char*)d_ws;
    const size_t SZQ = (size_t)32768 * 256 * 2;        // 16 MB each
    bf16* Qb  = (bf16*)(ws);
    bf16* Kb  = (bf16*)(ws + SZQ);
    bf16* Vb  = (bf16*)(ws + 2 * SZQ);
    bf16* xb  = (bf16*)(ws + 3 * SZQ);
    bf16* Wbt = (bf16*)(ws + 4 * SZQ);                  // 3*65536*2 = 384 KB
    float* sums = (float*)(ws + 4 * SZQ + 393216);      // 32768 f32

    hipMemsetAsync(out, 0, (size_t)out_size * sizeof(float), stream);
    hipMemsetAsync(sums, 0, 32768 * sizeof(float), stream);

    cvt_x<<<8192, 256, 0, stream>>>(x, xb);
    cvt_w<<<768, 256, 0, stream>>>(Wq, Wk, Wv, Wbt);
    qkv_gemm<<<dim3(512, 4, 3), 256, 0, stream>>>(xb, Wbt, Qb, Kb, Vb);
    attn<<<dim3(32, 28), 256, 0, stream>>>(Qb, Kb, Vb, out, sums);
    finalize<<<8192, 256, 0, stream>>>(out, sums);
}